// Round 2
// baseline (528.424 us; speedup 1.0000x reference)
//
#include <hip/hip_runtime.h>
#include <hip/hip_fp16.h>

// Problem constants
#define NF 32
#define DM 256
#define HH 128
#define BB 16
#define TT 512
#define BT 8192          // B*T tokens
#define OUT_W_OFF 2097152  // B*T*D
#define EPS 1e-5f

typedef __bf16 bf16x8 __attribute__((ext_vector_type(8)));
typedef float  f32x16 __attribute__((ext_vector_type(16)));
typedef __fp16 f16x2 __attribute__((ext_vector_type(2)));

__device__ __forceinline__ float eluf(float z){ return z > 0.f ? z : __expf(z) - 1.f; }
__device__ __forceinline__ float sigm(float z){ return 1.f/(1.f + __expf(-z)); }
__device__ __forceinline__ unsigned f2bf(float x){
  unsigned u = __float_as_uint(x);
  u += 0x7fffu + ((u>>16)&1u);   // RNE
  return u>>16;
}
__device__ __forceinline__ float rdlane(float v, int l){
  return __uint_as_float(__builtin_amdgcn_readlane(__float_as_uint(v), l));
}
// broadcast token-indexed value for MFMA C/D row r: m = (r&3)+8*(r>>2)+4*q
__device__ __forceinline__ float qsel(float v, int mb, int lane){
  float a0 = rdlane(v, mb), a1 = rdlane(v, mb+4);
  return (lane & 32) ? a1 : a0;
}

// Build A = elu(x*w1+b1) (M_TILES*32 tokens x 128 k) in MFMA A-frag order:
// Apack[mt][ks][lane][j] ; m=mt*32+(lane&31), k=ks*16+(lane>>5)*8+j
template<int MT>
__device__ __forceinline__ void build_A(uint4* Apack, const float* __restrict__ x,
                                        const float* __restrict__ w1, const float* __restrict__ b1,
                                        int f, int tok0, int tid){
  #pragma unroll
  for (int p = 0; p < MT*2; ++p){
    int slot = tid + p*256;
    int l  = slot & 63;
    int ks = (slot>>6)&7;
    int mt = slot>>9;
    int m  = mt*32 + (l&31);
    int k0 = ks*16 + (l>>5)*8;
    float xv = x[(tok0+m)*NF + f];
    const float* wp = w1 + f*HH + k0;
    const float* bp = b1 + f*HH + k0;
    float4 wa = *(const float4*)wp, wb = *(const float4*)(wp+4);
    float4 ba = *(const float4*)bp, bb = *(const float4*)(bp+4);
    float h0 = eluf(fmaf(xv, wa.x, ba.x));
    float h1 = eluf(fmaf(xv, wa.y, ba.y));
    float h2 = eluf(fmaf(xv, wa.z, ba.z));
    float h3 = eluf(fmaf(xv, wa.w, ba.w));
    float h4 = eluf(fmaf(xv, wb.x, bb.x));
    float h5 = eluf(fmaf(xv, wb.y, bb.y));
    float h6 = eluf(fmaf(xv, wb.z, bb.z));
    float h7 = eluf(fmaf(xv, wb.w, bb.w));
    uint4 pk;
    pk.x = f2bf(h0) | (f2bf(h1)<<16);
    pk.y = f2bf(h2) | (f2bf(h3)<<16);
    pk.z = f2bf(h4) | (f2bf(h5)<<16);
    pk.w = f2bf(h6) | (f2bf(h7)<<16);
    Apack[slot] = pk;
  }
}

// ---------------- prep: repack w2/wg (f32) -> bf16 B-fragment layout ----------------
// Wpk[f][c][nt][ks][lane][j]: k=ks*16+(lane>>5)*8+j, d=c*32+(lane&31), nt0=w2(proj) nt1=wg(gate)
__global__ __launch_bounds__(256) void k_prep(const float* __restrict__ w2,
                                              const float* __restrict__ wgm,
                                              uint4* __restrict__ Wpk){
  __shared__ float ssrc[2][128][32];
  const int tid = threadIdx.x;
  const int f = blockIdx.x, c = blockIdx.y;
  #pragma unroll
  for (int it = 0; it < 32; ++it){
    int idx = tid + it*256;
    int arr = idx >> 12;
    int rem = idx & 4095;
    int k = rem >> 5, dd = rem & 31;
    const float* src = arr ? wgm : w2;
    ssrc[arr][k][dd] = src[(f*HH + k)*DM + c*32 + dd];
  }
  __syncthreads();
  #pragma unroll
  for (int p = 0; p < 4; ++p){
    int oc = tid + p*256;
    int nt = oc>>9, ks = (oc>>6)&7, l = oc&63;
    int k0 = ks*16 + (l>>5)*8, dd = l&31;
    float v[8];
    #pragma unroll
    for (int j=0;j<8;++j) v[j] = ssrc[nt][k0+j][dd];
    uint4 pk;
    pk.x = f2bf(v[0]) | (f2bf(v[1])<<16);
    pk.y = f2bf(v[2]) | (f2bf(v[3])<<16);
    pk.z = f2bf(v[4]) | (f2bf(v[5])<<16);
    pk.w = f2bf(v[6]) | (f2bf(v[7])<<16);
    Wpk[(f*8 + c)*1024 + oc] = pk;
  }
}

// ---------------- pass1: GRN + LN stats + pooled sums ----------------
__global__ __launch_bounds__(256) void k_pass1(const float* __restrict__ x,  const float* __restrict__ w1,
    const float* __restrict__ b1, const float* __restrict__ b2, const float* __restrict__ bg,
    const float* __restrict__ wsk, const float* __restrict__ bsk,
    const float* __restrict__ lng, const float* __restrict__ lnb,
    const uint4* __restrict__ Wpk,
    float* __restrict__ pooled, float* __restrict__ muw, float* __restrict__ rsw){
  __shared__ uint4 Apack[2048];   // 32 KB: 128 tokens x 128 k
  __shared__ uint4 Bt[1024];      // 16 KB: one 32-d chunk (proj+gate)
  __shared__ float poolbuf[256];
  const int tid = threadIdx.x, lane = tid&63, wid = tid>>6;
  const int f = blockIdx.y;
  const int tok0 = blockIdx.x*128;
  const int b = tok0 >> 9;
  poolbuf[tid] = 0.f;
  build_A<4>(Apack, x, w1, b1, f, tok0, tid);
  __syncthreads();
  bf16x8 afr[8];
  #pragma unroll
  for (int ks=0; ks<8; ++ks) afr[ks] = __builtin_bit_cast(bf16x8, Apack[(wid*8+ks)*64 + lane]);
  const int col = lane&31;
  float xl = x[(tok0 + wid*32 + col)*NF + f];
  float sum[16], ssq[16];
  #pragma unroll
  for (int r=0;r<16;++r){ sum[r]=0.f; ssq[r]=0.f; }
  unsigned spk[8][8];
  #pragma unroll
  for (int c=0; c<8; ++c){
    {
      const uint4* src = Wpk + (f*8 + c)*1024;
      #pragma unroll
      for (int p=0;p<4;++p) Bt[tid + p*256] = src[tid + p*256];
    }
    __syncthreads();
    f32x16 acc0 = {0.f}, acc1 = {0.f};
    #pragma unroll
    for (int ks=0;ks<8;++ks){
      bf16x8 bf0 = __builtin_bit_cast(bf16x8, Bt[ks*64 + lane]);
      bf16x8 bf1 = __builtin_bit_cast(bf16x8, Bt[512 + ks*64 + lane]);
      acc0 = __builtin_amdgcn_mfma_f32_32x32x16_bf16(afr[ks], bf0, acc0, 0,0,0);
      acc1 = __builtin_amdgcn_mfma_f32_32x32x16_bf16(afr[ks], bf1, acc1, 0,0,0);
    }
    __syncthreads();
    const int d = c*32 + col;
    const float b2v = b2[f*DM+d], bgv = bg[f*DM+d];
    const float wsv = wsk[f*DM+d], bsv = bsk[f*DM+d];
    #pragma unroll
    for (int i=0;i<8;++i){
      const int r0 = 2*i, r1 = 2*i+1;
      int mb0 = (r0&3)+8*(r0>>2);
      int mb1 = (r1&3)+8*(r1>>2);
      float xr0 = qsel(xl, mb0, lane);
      float xr1 = qsel(xl, mb1, lane);
      float p0 = acc0[r0] + b2v;
      float p1 = acc0[r1] + b2v;
      float g0 = sigm(acc1[r0] + bgv);
      float g1 = sigm(acc1[r1] + bgv);
      float sv0 = fmaf(xr0, wsv, bsv) + g0*p0;
      float sv1 = fmaf(xr1, wsv, bsv) + g1*p1;
      sum[r0] += sv0; ssq[r0] = fmaf(sv0, sv0, ssq[r0]);
      sum[r1] += sv1; ssq[r1] = fmaf(sv1, sv1, ssq[r1]);
      f16x2 pr = __builtin_amdgcn_cvt_pkrtz(sv0, sv1);
      spk[c][i] = __builtin_bit_cast(unsigned, pr);
    }
  }
  // LN stats: butterfly over the 32 cols in each q-half; sum[r]->mu, ssq[r]->rsigma
  #pragma unroll
  for (int r=0;r<16;++r){
    float s1 = sum[r], s2 = ssq[r];
    s1 += __shfl_xor(s1,1);  s2 += __shfl_xor(s2,1);
    s1 += __shfl_xor(s1,2);  s2 += __shfl_xor(s2,2);
    s1 += __shfl_xor(s1,4);  s2 += __shfl_xor(s2,4);
    s1 += __shfl_xor(s1,8);  s2 += __shfl_xor(s2,8);
    s1 += __shfl_xor(s1,16); s2 += __shfl_xor(s2,16);
    float mu = s1 * (1.f/256.f);
    float var = fmaf(-mu, mu, s2*(1.f/256.f));
    sum[r] = mu;
    ssq[r] = rsqrtf(fmaxf(var, 0.f) + EPS);
  }
  if (col == 0){
    const int q = lane>>5;
    #pragma unroll
    for (int r=0;r<16;++r){
      int m = (r&3) + 8*(r>>2) + 4*q;
      int tok = tok0 + wid*32 + m;
      muw[f*BT + tok] = sum[r];
      rsw[f*BT + tok] = ssq[r];
    }
  }
  // pooled accumulation (post-LN), LDS combine then one global atomic per d
  #pragma unroll
  for (int c=0;c<8;++c){
    const int d = c*32+col;
    const float gv = lng[f*DM+d], bv = lnb[f*DM+d];
    float ps = 0.f;
    #pragma unroll
    for (int i=0;i<8;++i){
      f16x2 pr = __builtin_bit_cast(f16x2, spk[c][i]);
      float sv0 = (float)pr[0], sv1 = (float)pr[1];
      ps += fmaf((sv0 - sum[2*i  ])*ssq[2*i  ], gv, bv);
      ps += fmaf((sv1 - sum[2*i+1])*ssq[2*i+1], gv, bv);
    }
    ps += __shfl_xor(ps, 32);
    if (lane < 32) atomicAdd(&poolbuf[d], ps);
  }
  __syncthreads();
  atomicAdd(&pooled[b*8192 + f*DM + tid], poolbuf[tid]);
}

// ---------------- pass2a: flat_pooled @ W1 / @ Ws (split-K partials) ----------------
__global__ __launch_bounds__(256) void k_pass2a(const float* __restrict__ pooled,
    const float* __restrict__ W1, const float* __restrict__ Wsm,
    float* __restrict__ hw_pre, float* __restrict__ sk_pre){
  __shared__ float fl[512];
  const int tid = threadIdx.x;
  const int b = blockIdx.x;
  const int k0 = blockIdx.y * 512;
  fl[tid]       = pooled[b*8192 + k0 + tid]       * (1.f/512.f);
  fl[tid+256]   = pooled[b*8192 + k0 + tid + 256] * (1.f/512.f);
  __syncthreads();
  float acc = 0.f;
  const float* wcol = W1 + (size_t)k0*DM + tid;
  #pragma unroll 4
  for (int i=0;i<512;++i) acc = fmaf(fl[i], wcol[(size_t)i*DM], acc);
  atomicAdd(&hw_pre[b*DM + tid], acc);
  const int colj = tid & 31, sub = tid >> 5;
  float acc2 = 0.f;
  const float* wscol = Wsm + (size_t)(k0 + sub*64)*NF + colj;
  const float* fls = fl + sub*64;
  #pragma unroll 4
  for (int i=0;i<64;++i) acc2 = fmaf(fls[i], wscol[(size_t)i*NF], acc2);
  atomicAdd(&sk_pre[b*NF + colj], acc2);
}

// ---------------- pass2b: weight GRN + LN + softmax -> weights ----------------
__global__ __launch_bounds__(64) void k_pass2b(const float* __restrict__ hw_pre, const float* __restrict__ sk_pre,
    const float* __restrict__ B1, const float* __restrict__ W2, const float* __restrict__ B2,
    const float* __restrict__ Wg, const float* __restrict__ Bg, const float* __restrict__ Bs,
    const float* __restrict__ LNg, const float* __restrict__ LNb,
    float* __restrict__ out, float* __restrict__ wsel){
  __shared__ float hw[256];
  const int tid = threadIdx.x, b = blockIdx.x;
  for (int i=tid;i<256;i+=64) hw[i] = eluf(hw_pre[b*DM+i] + B1[i]);
  __syncthreads();
  if (tid < 32){
    const int j = tid;
    float ap = B2[j], ag = Bg[j];
    #pragma unroll 4
    for (int i=0;i<256;++i){ float h = hw[i]; ap = fmaf(h, W2[i*NF+j], ap); ag = fmaf(h, Wg[i*NF+j], ag); }
    float gw = sigm(ag);
    float v = sk_pre[b*NF+j] + Bs[j] + gw*ap;
    float s1 = v;
    s1 += __shfl_xor(s1,1); s1 += __shfl_xor(s1,2); s1 += __shfl_xor(s1,4); s1 += __shfl_xor(s1,8); s1 += __shfl_xor(s1,16);
    float mean = s1*(1.f/32.f);
    float dv = v - mean;
    float s2 = dv*dv;
    s2 += __shfl_xor(s2,1); s2 += __shfl_xor(s2,2); s2 += __shfl_xor(s2,4); s2 += __shfl_xor(s2,8); s2 += __shfl_xor(s2,16);
    float wn = fmaf(dv * rsqrtf(s2*(1.f/32.f) + EPS), LNg[j], LNb[j]);
    float mx = wn;
    mx = fmaxf(mx, __shfl_xor(mx,1)); mx = fmaxf(mx, __shfl_xor(mx,2)); mx = fmaxf(mx, __shfl_xor(mx,4));
    mx = fmaxf(mx, __shfl_xor(mx,8)); mx = fmaxf(mx, __shfl_xor(mx,16));
    float e = __expf(wn - mx);
    float se = e;
    se += __shfl_xor(se,1); se += __shfl_xor(se,2); se += __shfl_xor(se,4); se += __shfl_xor(se,8); se += __shfl_xor(se,16);
    float wgt = e / se;
    out[OUT_W_OFF + b*NF + j] = wgt;
    wsel[b*NF + j] = wgt;
  }
}

// ---------------- pass3: recompute stacked, weighted combine over f ----------------
__global__ __launch_bounds__(256) void k_pass3(const float* __restrict__ x,  const float* __restrict__ w1,
    const float* __restrict__ b1, const float* __restrict__ b2, const float* __restrict__ bg,
    const float* __restrict__ wsk, const float* __restrict__ bsk,
    const float* __restrict__ lng, const float* __restrict__ lnb,
    const uint4* __restrict__ Wpk, const float* __restrict__ muw, const float* __restrict__ rsw,
    const float* __restrict__ wsel, float* __restrict__ out){
  __shared__ uint4 Apack[1024];   // 16 KB: 64 tokens x 128 k
  __shared__ uint4 Bt[2048];      // 32 KB: two 32-d chunks
  const int tid = threadIdx.x, lane = tid&63, wid = tid>>6;
  const int tok0 = blockIdx.x*64;
  const int b = tok0>>9;
  const int cp = blockIdx.y;          // 0..3
  const int mt = wid & 1;
  const int ci = wid >> 1;            // which of the two staged chunks
  const int c = cp*2 + ci;            // 0..7
  const int col = lane & 31;
  const int d = c*32 + col;
  float sel[16];
  #pragma unroll
  for (int r=0;r<16;++r) sel[r]=0.f;
  for (int f=0; f<NF; ++f){
    __syncthreads();   // all reads of Apack/Bt from previous f done
    build_A<2>(Apack, x, w1, b1, f, tok0, tid);
    {
      const uint4* src = Wpk + (f*8 + cp*2)*1024;
      #pragma unroll
      for (int p=0;p<8;++p) Bt[tid + p*256] = src[tid + p*256];
    }
    __syncthreads();
    bf16x8 afr[8];
    #pragma unroll
    for (int ks=0;ks<8;++ks) afr[ks] = __builtin_bit_cast(bf16x8, Apack[(mt*8+ks)*64 + lane]);
    float xl  = x[(tok0 + mt*32 + col)*NF + f];
    float mul = muw[f*BT + tok0 + mt*32 + col];
    float rsl = rsw[f*BT + tok0 + mt*32 + col];
    f32x16 acc0 = {0.f}, acc1 = {0.f};
    const uint4* bsec = Bt + ci*1024;
    #pragma unroll
    for (int ks=0;ks<8;++ks){
      bf16x8 bf0 = __builtin_bit_cast(bf16x8, bsec[ks*64+lane]);
      bf16x8 bf1 = __builtin_bit_cast(bf16x8, bsec[512 + ks*64+lane]);
      acc0 = __builtin_amdgcn_mfma_f32_32x32x16_bf16(afr[ks], bf0, acc0, 0,0,0);
      acc1 = __builtin_amdgcn_mfma_f32_32x32x16_bf16(afr[ks], bf1, acc1, 0,0,0);
    }
    const float wv  = wsel[b*NF + f];
    const float b2v = b2[f*DM+d], bgv = bg[f*DM+d];
    const float wsv = wsk[f*DM+d], bsv = bsk[f*DM+d];
    const float gv  = lng[f*DM+d], bv = lnb[f*DM+d];
    #pragma unroll
    for (int r=0;r<16;++r){
      int mb = (r&3)+8*(r>>2);
      float xr  = qsel(xl,  mb, lane);
      float mur = qsel(mul, mb, lane);
      float rsr = qsel(rsl, mb, lane);
      float proj = acc0[r] + b2v;
      float gate = sigm(acc1[r] + bgv);
      float sv = fmaf(xr, wsv, bsv) + gate*proj;
      float sh = fmaf((sv - mur)*rsr, gv, bv);
      sel[r] = fmaf(wv, sh, sel[r]);
    }
  }
  const int q = lane>>5;
  #pragma unroll
  for (int r=0;r<16;++r){
    int m = (r&3)+8*(r>>2)+4*q;
    out[(size_t)(tok0 + mt*32 + m)*DM + d] = sel[r];
  }
}

extern "C" void kernel_launch(void* const* d_in, const int* in_sizes, int n_in,
                              void* d_out, int out_size, void* d_ws, size_t ws_size,
                              hipStream_t stream) {
  const float* x   = (const float*)d_in[0];
  const float* w1  = (const float*)d_in[1];
  const float* b1  = (const float*)d_in[2];
  const float* w2  = (const float*)d_in[3];
  const float* b2  = (const float*)d_in[4];
  const float* wgm = (const float*)d_in[5];
  const float* bg  = (const float*)d_in[6];
  const float* wsk = (const float*)d_in[7];
  const float* bsk = (const float*)d_in[8];
  const float* lng = (const float*)d_in[9];
  const float* lnb = (const float*)d_in[10];
  const float* W1  = (const float*)d_in[11];
  const float* B1  = (const float*)d_in[12];
  const float* W2  = (const float*)d_in[13];
  const float* B2  = (const float*)d_in[14];
  const float* Wg  = (const float*)d_in[15];
  const float* Bg  = (const float*)d_in[16];
  const float* Wsm = (const float*)d_in[17];
  const float* Bs  = (const float*)d_in[18];
  const float* LNg = (const float*)d_in[19];
  const float* LNb = (const float*)d_in[20];
  float* out = (float*)d_out;

  char* ws = (char*)d_ws;
  uint4* Wpk    = (uint4*)ws;                    // 4 MB bf16-packed weights
  float* pooled = (float*)(ws + 4194304);        // 512 KB
  float* muw    = (float*)(ws + 4718592);        // 1 MB
  float* rsw    = (float*)(ws + 5767168);        // 1 MB
  float* hw_pre = (float*)(ws + 6815744);        // 16 KB
  float* sk_pre = (float*)(ws + 6832128);        // 2 KB
  float* wsel   = (float*)(ws + 6834176);        // 2 KB

  (void)hipMemsetAsync(pooled, 0, 524288, stream);
  (void)hipMemsetAsync(hw_pre, 0, 16384 + 2048, stream);

  k_prep<<<dim3(32,8), 256, 0, stream>>>(w2, wgm, Wpk);
  k_pass1<<<dim3(64,32), 256, 0, stream>>>(x, w1, b1, b2, bg, wsk, bsk, lng, lnb,
                                           Wpk, pooled, muw, rsw);
  k_pass2a<<<dim3(16,16), 256, 0, stream>>>(pooled, W1, Wsm, hw_pre, sk_pre);
  k_pass2b<<<16, 64, 0, stream>>>(hw_pre, sk_pre, B1, W2, B2, Wg, Bg, Bs, LNg, LNb, out, wsel);
  k_pass3<<<dim3(128,4), 256, 0, stream>>>(x, w1, b1, b2, bg, wsk, bsk, lng, lnb,
                                           Wpk, muw, rsw, wsel, out);
}

// Round 3
// 381.117 us; speedup vs baseline: 1.3865x; 1.3865x over previous
//
#include <hip/hip_runtime.h>
#include <hip/hip_fp16.h>

// Problem constants
#define NF 32
#define DM 256
#define HH 128
#define BB 16
#define TT 512
#define BT 8192            // B*T tokens
#define OUT_W_OFF 2097152  // B*T*D
#define EPS 1e-5f

typedef __bf16 bf16x8 __attribute__((ext_vector_type(8)));
typedef float  f32x16 __attribute__((ext_vector_type(16)));
typedef __fp16 f16x2 __attribute__((ext_vector_type(2)));
typedef __fp16 f16x8 __attribute__((ext_vector_type(8)));

__device__ __forceinline__ float eluf(float z){ return z > 0.f ? z : __expf(z) - 1.f; }
__device__ __forceinline__ float sigm(float z){ return 1.f/(1.f + __expf(-z)); }
__device__ __forceinline__ unsigned f2bf(float x){
  unsigned u = __float_as_uint(x);
  u += 0x7fffu + ((u>>16)&1u);   // RNE
  return u>>16;
}
__device__ __forceinline__ float rdlane(float v, int l){
  return __uint_as_float(__builtin_amdgcn_readlane(__float_as_uint(v), l));
}
// broadcast token-indexed value for MFMA C/D row r: m = (r&3)+8*(r>>2)+4*q
__device__ __forceinline__ float qsel(float v, int mb, int lane){
  float a0 = rdlane(v, mb), a1 = rdlane(v, mb+4);
  return (lane & 32) ? a1 : a0;
}

// Build A = elu(x*w1+b1) (MT*32 tokens x 128 k) in MFMA A-frag order:
// Apack[mt][ks][lane][j] ; m=mt*32+(lane&31), k=ks*16+(lane>>5)*8+j
template<int MT>
__device__ __forceinline__ void build_A(uint4* Apack, const float* __restrict__ x,
                                        const float* __restrict__ w1, const float* __restrict__ b1,
                                        int f, int tok0, int tid){
  #pragma unroll
  for (int p = 0; p < MT*2; ++p){
    int slot = tid + p*256;
    int l  = slot & 63;
    int ks = (slot>>6)&7;
    int mt = slot>>9;
    int m  = mt*32 + (l&31);
    int k0 = ks*16 + (l>>5)*8;
    float xv = x[(tok0+m)*NF + f];
    const float* wp = w1 + f*HH + k0;
    const float* bp = b1 + f*HH + k0;
    float4 wa = *(const float4*)wp, wb = *(const float4*)(wp+4);
    float4 ba = *(const float4*)bp, bb = *(const float4*)(bp+4);
    float h0 = eluf(fmaf(xv, wa.x, ba.x));
    float h1 = eluf(fmaf(xv, wa.y, ba.y));
    float h2 = eluf(fmaf(xv, wa.z, ba.z));
    float h3 = eluf(fmaf(xv, wa.w, ba.w));
    float h4 = eluf(fmaf(xv, wb.x, bb.x));
    float h5 = eluf(fmaf(xv, wb.y, bb.y));
    float h6 = eluf(fmaf(xv, wb.z, bb.z));
    float h7 = eluf(fmaf(xv, wb.w, bb.w));
    uint4 pk;
    pk.x = f2bf(h0) | (f2bf(h1)<<16);
    pk.y = f2bf(h2) | (f2bf(h3)<<16);
    pk.z = f2bf(h4) | (f2bf(h5)<<16);
    pk.w = f2bf(h6) | (f2bf(h7)<<16);
    Apack[slot] = pk;
  }
}

// ---------------- prep: repack w2/wg (f32) -> bf16 B-fragment layout ----------------
__global__ __launch_bounds__(256) void k_prep(const float* __restrict__ w2,
                                              const float* __restrict__ wgm,
                                              uint4* __restrict__ Wpk){
  __shared__ float ssrc[2][128][32];
  const int tid = threadIdx.x;
  const int f = blockIdx.x, c = blockIdx.y;
  #pragma unroll
  for (int it = 0; it < 32; ++it){
    int idx = tid + it*256;
    int arr = idx >> 12;
    int rem = idx & 4095;
    int k = rem >> 5, dd = rem & 31;
    const float* src = arr ? wgm : w2;
    ssrc[arr][k][dd] = src[(f*HH + k)*DM + c*32 + dd];
  }
  __syncthreads();
  #pragma unroll
  for (int p = 0; p < 4; ++p){
    int oc = tid + p*256;
    int nt = oc>>9, ks = (oc>>6)&7, l = oc&63;
    int k0 = ks*16 + (l>>5)*8, dd = l&31;
    float v[8];
    #pragma unroll
    for (int j=0;j<8;++j) v[j] = ssrc[nt][k0+j][dd];
    uint4 pk;
    pk.x = f2bf(v[0]) | (f2bf(v[1])<<16);
    pk.y = f2bf(v[2]) | (f2bf(v[3])<<16);
    pk.z = f2bf(v[4]) | (f2bf(v[5])<<16);
    pk.w = f2bf(v[6]) | (f2bf(v[7])<<16);
    Wpk[(f*8 + c)*1024 + oc] = pk;
  }
}

// ---------------- pass1: GRN + LN + store shat(fp16) + pooled sums ----------------
__global__ __launch_bounds__(256) void k_pass1(const float* __restrict__ x,  const float* __restrict__ w1,
    const float* __restrict__ b1, const float* __restrict__ b2, const float* __restrict__ bg,
    const float* __restrict__ wsk, const float* __restrict__ bsk,
    const float* __restrict__ lng, const float* __restrict__ lnb,
    const uint4* __restrict__ Wpk,
    float* __restrict__ pooled, uint4* __restrict__ stk4){
  __shared__ uint4 Apack[2048];   // 32 KB: 128 tokens x 128 k; reused as fp16 stage
  __shared__ uint4 Bt[1024];      // 16 KB: one 32-d chunk (proj+gate)
  __shared__ float poolbuf[256];
  const int tid = threadIdx.x, lane = tid&63, wid = tid>>6;
  const int f = blockIdx.y;
  const int tok0 = blockIdx.x*128;
  const int b = tok0 >> 9;
  poolbuf[tid] = 0.f;
  build_A<4>(Apack, x, w1, b1, f, tok0, tid);
  __syncthreads();
  bf16x8 afr[8];
  #pragma unroll
  for (int ks=0; ks<8; ++ks) afr[ks] = __builtin_bit_cast(bf16x8, Apack[(wid*8+ks)*64 + lane]);
  const int col = lane&31;
  const int q = lane>>5;
  float xl = x[(tok0 + wid*32 + col)*NF + f];
  float sum[16], ssq[16];
  #pragma unroll
  for (int r=0;r<16;++r){ sum[r]=0.f; ssq[r]=0.f; }
  unsigned spk[8][8];
  #pragma unroll
  for (int c=0; c<8; ++c){
    {
      const uint4* src = Wpk + (f*8 + c)*1024;
      #pragma unroll
      for (int p=0;p<4;++p) Bt[tid + p*256] = src[tid + p*256];
    }
    __syncthreads();
    f32x16 acc0 = {0.f}, acc1 = {0.f};
    #pragma unroll
    for (int ks=0;ks<8;++ks){
      bf16x8 bf0 = __builtin_bit_cast(bf16x8, Bt[ks*64 + lane]);
      bf16x8 bf1 = __builtin_bit_cast(bf16x8, Bt[512 + ks*64 + lane]);
      acc0 = __builtin_amdgcn_mfma_f32_32x32x16_bf16(afr[ks], bf0, acc0, 0,0,0);
      acc1 = __builtin_amdgcn_mfma_f32_32x32x16_bf16(afr[ks], bf1, acc1, 0,0,0);
    }
    __syncthreads();
    const int d = c*32 + col;
    const float b2v = b2[f*DM+d], bgv = bg[f*DM+d];
    const float wsv = wsk[f*DM+d], bsv = bsk[f*DM+d];
    #pragma unroll
    for (int i=0;i<8;++i){
      const int r0 = 2*i, r1 = 2*i+1;
      int mb0 = (r0&3)+8*(r0>>2);
      int mb1 = (r1&3)+8*(r1>>2);
      float xr0 = qsel(xl, mb0, lane);
      float xr1 = qsel(xl, mb1, lane);
      float p0 = acc0[r0] + b2v;
      float p1 = acc0[r1] + b2v;
      float g0 = sigm(acc1[r0] + bgv);
      float g1 = sigm(acc1[r1] + bgv);
      float sv0 = fmaf(xr0, wsv, bsv) + g0*p0;
      float sv1 = fmaf(xr1, wsv, bsv) + g1*p1;
      sum[r0] += sv0; ssq[r0] = fmaf(sv0, sv0, ssq[r0]);
      sum[r1] += sv1; ssq[r1] = fmaf(sv1, sv1, ssq[r1]);
      f16x2 pr = __builtin_amdgcn_cvt_pkrtz(sv0, sv1);
      spk[c][i] = __builtin_bit_cast(unsigned, pr);
    }
  }
  // LN stats: butterfly over 32 cols in each q-half; sum[r]->mu, ssq[r]->rsigma
  #pragma unroll
  for (int r=0;r<16;++r){
    float s1 = sum[r], s2 = ssq[r];
    s1 += __shfl_xor(s1,1);  s2 += __shfl_xor(s2,1);
    s1 += __shfl_xor(s1,2);  s2 += __shfl_xor(s2,2);
    s1 += __shfl_xor(s1,4);  s2 += __shfl_xor(s2,4);
    s1 += __shfl_xor(s1,8);  s2 += __shfl_xor(s2,8);
    s1 += __shfl_xor(s1,16); s2 += __shfl_xor(s2,16);
    float mu = s1 * (1.f/256.f);
    float var = fmaf(-mu, mu, s2*(1.f/256.f));
    sum[r] = mu;
    ssq[r] = rsqrtf(fmaxf(var, 0.f) + EPS);
  }
  // apply LN, stage fp16 shat in LDS (reusing Apack), dump coalesced to stk,
  // and accumulate pooled sums. Two halves of 4 d-chunks (32 KB stage each).
  __fp16* stage = (__fp16*)Apack;   // [128 t][128 d]
  uint4*  stg4  = (uint4*)Apack;
  #pragma unroll
  for (int h=0; h<2; ++h){
    __syncthreads();   // stage buffer free (frags/prev dump consumed)
    #pragma unroll
    for (int cc=0; cc<4; ++cc){
      const int c = h*4 + cc;
      const int d = c*32 + col;
      const float gv = lng[f*DM+d], bv = lnb[f*DM+d];
      float ps = 0.f;
      #pragma unroll
      for (int i=0;i<8;++i){
        f16x2 pr = __builtin_bit_cast(f16x2, spk[c][i]);
        float sh0 = fmaf(((float)pr[0] - sum[2*i  ])*ssq[2*i  ], gv, bv);
        float sh1 = fmaf(((float)pr[1] - sum[2*i+1])*ssq[2*i+1], gv, bv);
        int m0 = ((2*i)&3) + 8*((2*i)>>2) + 4*q;   // even; row m1 = m0+1
        int t0 = wid*32 + m0;
        stage[ t0   *128 + cc*32 + col] = (__fp16)sh0;
        stage[(t0+1)*128 + cc*32 + col] = (__fp16)sh1;
        ps += sh0 + sh1;
      }
      ps += __shfl_xor(ps, 32);
      if (lane < 32) atomicAdd(&poolbuf[d], ps);
    }
    __syncthreads();
    // dump 32 KB stage -> stk[f][tok0..tok0+128][h*128..+128) fp16, fully coalesced
    #pragma unroll
    for (int p=0;p<8;++p){
      int slot = tid + p*256;                 // 2048 slots of 16 B
      stk4[(size_t)f*262144 + (size_t)(tok0 + (slot>>4))*32 + h*16 + (slot&15)] = stg4[slot];
    }
  }
  __syncthreads();
  atomicAdd(&pooled[b*8192 + f*DM + tid], poolbuf[tid]);
}

// ---------------- pass2a: flat_pooled @ W1 / @ Ws (split-K partials) ----------------
__global__ __launch_bounds__(256) void k_pass2a(const float* __restrict__ pooled,
    const float* __restrict__ W1, const float* __restrict__ Wsm,
    float* __restrict__ hw_pre, float* __restrict__ sk_pre){
  __shared__ float fl[512];
  const int tid = threadIdx.x;
  const int b = blockIdx.x;
  const int k0 = blockIdx.y * 512;
  fl[tid]       = pooled[b*8192 + k0 + tid]       * (1.f/512.f);
  fl[tid+256]   = pooled[b*8192 + k0 + tid + 256] * (1.f/512.f);
  __syncthreads();
  float acc = 0.f;
  const float* wcol = W1 + (size_t)k0*DM + tid;
  #pragma unroll 4
  for (int i=0;i<512;++i) acc = fmaf(fl[i], wcol[(size_t)i*DM], acc);
  atomicAdd(&hw_pre[b*DM + tid], acc);
  const int colj = tid & 31, sub = tid >> 5;
  float acc2 = 0.f;
  const float* wscol = Wsm + (size_t)(k0 + sub*64)*NF + colj;
  const float* fls = fl + sub*64;
  #pragma unroll 4
  for (int i=0;i<64;++i) acc2 = fmaf(fls[i], wscol[(size_t)i*NF], acc2);
  atomicAdd(&sk_pre[b*NF + colj], acc2);
}

// ---------------- pass2b: weight GRN + LN + softmax -> weights ----------------
__global__ __launch_bounds__(64) void k_pass2b(const float* __restrict__ hw_pre, const float* __restrict__ sk_pre,
    const float* __restrict__ B1, const float* __restrict__ W2, const float* __restrict__ B2,
    const float* __restrict__ Wg, const float* __restrict__ Bg, const float* __restrict__ Bs,
    const float* __restrict__ LNg, const float* __restrict__ LNb,
    float* __restrict__ out, float* __restrict__ wsel){
  __shared__ float hw[256];
  const int tid = threadIdx.x, b = blockIdx.x;
  for (int i=tid;i<256;i+=64) hw[i] = eluf(hw_pre[b*DM+i] + B1[i]);
  __syncthreads();
  if (tid < 32){
    const int j = tid;
    float ap = B2[j], ag = Bg[j];
    #pragma unroll 4
    for (int i=0;i<256;++i){ float h = hw[i]; ap = fmaf(h, W2[i*NF+j], ap); ag = fmaf(h, Wg[i*NF+j], ag); }
    float gw = sigm(ag);
    float v = sk_pre[b*NF+j] + Bs[j] + gw*ap;
    float s1 = v;
    s1 += __shfl_xor(s1,1); s1 += __shfl_xor(s1,2); s1 += __shfl_xor(s1,4); s1 += __shfl_xor(s1,8); s1 += __shfl_xor(s1,16);
    float mean = s1*(1.f/32.f);
    float dv = v - mean;
    float s2 = dv*dv;
    s2 += __shfl_xor(s2,1); s2 += __shfl_xor(s2,2); s2 += __shfl_xor(s2,4); s2 += __shfl_xor(s2,8); s2 += __shfl_xor(s2,16);
    float wn = fmaf(dv * rsqrtf(s2*(1.f/32.f) + EPS), LNg[j], LNb[j]);
    float mx = wn;
    mx = fmaxf(mx, __shfl_xor(mx,1)); mx = fmaxf(mx, __shfl_xor(mx,2)); mx = fmaxf(mx, __shfl_xor(mx,4));
    mx = fmaxf(mx, __shfl_xor(mx,8)); mx = fmaxf(mx, __shfl_xor(mx,16));
    float e = __expf(wn - mx);
    float se = e;
    se += __shfl_xor(se,1); se += __shfl_xor(se,2); se += __shfl_xor(se,4); se += __shfl_xor(se,8); se += __shfl_xor(se,16);
    float wgt = e / se;
    out[OUT_W_OFF + b*NF + j] = wgt;
    wsel[b*NF + j] = wgt;
  }
}

// ---------------- combine: out[t,d] = sum_f w[b,f] * shat[f,t,d] ----------------
__global__ __launch_bounds__(256) void k_comb(const uint4* __restrict__ stk4,
    const float* __restrict__ wsel, float* __restrict__ out){
  const int tid = threadIdx.x;
  const int t = blockIdx.x*8 + (tid >> 5);   // 8 tokens per block
  const int oct = tid & 31;                  // 8-d group within the 256-d row
  const int b = t >> 9;
  float acc[8];
  #pragma unroll
  for (int j=0;j<8;++j) acc[j]=0.f;
  #pragma unroll 4
  for (int f=0; f<NF; ++f){
    float wf = wsel[b*NF + f];
    uint4 v = stk4[(size_t)f*262144 + (size_t)t*32 + oct];
    f16x8 hv = __builtin_bit_cast(f16x8, v);
    #pragma unroll
    for (int j=0;j<8;++j) acc[j] = fmaf(wf, (float)hv[j], acc[j]);
  }
  float4* o = (float4*)(out + (size_t)t*DM + oct*8);
  o[0] = make_float4(acc[0],acc[1],acc[2],acc[3]);
  o[1] = make_float4(acc[4],acc[5],acc[6],acc[7]);
}

extern "C" void kernel_launch(void* const* d_in, const int* in_sizes, int n_in,
                              void* d_out, int out_size, void* d_ws, size_t ws_size,
                              hipStream_t stream) {
  const float* x   = (const float*)d_in[0];
  const float* w1  = (const float*)d_in[1];
  const float* b1  = (const float*)d_in[2];
  const float* w2  = (const float*)d_in[3];
  const float* b2  = (const float*)d_in[4];
  const float* wgm = (const float*)d_in[5];
  const float* bg  = (const float*)d_in[6];
  const float* wsk = (const float*)d_in[7];
  const float* bsk = (const float*)d_in[8];
  const float* lng = (const float*)d_in[9];
  const float* lnb = (const float*)d_in[10];
  const float* W1  = (const float*)d_in[11];
  const float* B1  = (const float*)d_in[12];
  const float* W2  = (const float*)d_in[13];
  const float* B2  = (const float*)d_in[14];
  const float* Wg  = (const float*)d_in[15];
  const float* Bg  = (const float*)d_in[16];
  const float* Wsm = (const float*)d_in[17];
  const float* Bs  = (const float*)d_in[18];
  const float* LNg = (const float*)d_in[19];
  const float* LNb = (const float*)d_in[20];
  float* out = (float*)d_out;

  char* ws = (char*)d_ws;
  uint4* Wpk    = (uint4*)ws;                     // 4 MB bf16-packed weights
  uint4* stk4   = (uint4*)(ws + 4194304);         // 128 MB fp16 shat [f][t][d]
  float* pooled = (float*)(ws + 138412032);       // 512 KB
  float* hw_pre = (float*)(ws + 138936320);       // 16 KB
  float* sk_pre = (float*)(ws + 138952704);       // 2 KB
  float* wsel   = (float*)(ws + 138954752);       // 2 KB

  (void)hipMemsetAsync(pooled, 0, 524288, stream);
  (void)hipMemsetAsync(hw_pre, 0, 16384 + 2048, stream);

  k_prep<<<dim3(32,8), 256, 0, stream>>>(w2, wgm, Wpk);
  k_pass1<<<dim3(64,32), 256, 0, stream>>>(x, w1, b1, b2, bg, wsk, bsk, lng, lnb,
                                           Wpk, pooled, stk4);
  k_pass2a<<<dim3(16,16), 256, 0, stream>>>(pooled, W1, Wsm, hw_pre, sk_pre);
  k_pass2b<<<16, 64, 0, stream>>>(hw_pre, sk_pre, B1, W2, B2, Wg, Bg, Bs, LNg, LNb, out, wsel);
  k_comb<<<1024, 256, 0, stream>>>(stk4, wsel, out);
}

// Round 4
// 321.010 us; speedup vs baseline: 1.6461x; 1.1872x over previous
//
#include <hip/hip_runtime.h>
#include <hip/hip_fp16.h>

// Problem constants
#define NF 32
#define DM 256
#define HH 128
#define BB 16
#define TT 512
#define BT 8192            // B*T tokens
#define OUT_W_OFF 2097152  // B*T*D
#define EPS 1e-5f

typedef __bf16 bf16x8 __attribute__((ext_vector_type(8)));
typedef float  f32x16 __attribute__((ext_vector_type(16)));
typedef __fp16 f16x2 __attribute__((ext_vector_type(2)));
typedef __fp16 f16x8 __attribute__((ext_vector_type(8)));

__device__ __forceinline__ float eluf(float z){ return z > 0.f ? z : __expf(z) - 1.f; }
__device__ __forceinline__ float sigm(float z){ return 1.f/(1.f + __expf(-z)); }
__device__ __forceinline__ unsigned f2bf(float x){
  unsigned u = __float_as_uint(x);
  u += 0x7fffu + ((u>>16)&1u);   // RNE
  return u>>16;
}
__device__ __forceinline__ float rdlane(float v, int l){
  return __uint_as_float(__builtin_amdgcn_readlane(__float_as_uint(v), l));
}
// broadcast token-indexed value for MFMA C/D row r: m = (r&3)+8*(r>>2)+4*q
__device__ __forceinline__ float qsel(float v, int mb, int lane){
  float a0 = rdlane(v, mb), a1 = rdlane(v, mb+4);
  return (lane & 32) ? a1 : a0;
}

// Build A = elu(x*w1+b1) (MT*32 tokens x 128 k) in MFMA A-frag order:
// Apack[mt][ks][lane][j] ; m=mt*32+(lane&31), k=ks*16+(lane>>5)*8+j
template<int MT>
__device__ __forceinline__ void build_A(uint4* Apack, const float* __restrict__ x,
                                        const float* __restrict__ w1, const float* __restrict__ b1,
                                        int f, int tok0, int tid){
  #pragma unroll
  for (int p = 0; p < MT*2; ++p){
    int slot = tid + p*256;
    int l  = slot & 63;
    int ks = (slot>>6)&7;
    int mt = slot>>9;
    int m  = mt*32 + (l&31);
    int k0 = ks*16 + (l>>5)*8;
    float xv = x[(tok0+m)*NF + f];
    const float* wp = w1 + f*HH + k0;
    const float* bp = b1 + f*HH + k0;
    float4 wa = *(const float4*)wp, wb = *(const float4*)(wp+4);
    float4 ba = *(const float4*)bp, bb = *(const float4*)(bp+4);
    float h0 = eluf(fmaf(xv, wa.x, ba.x));
    float h1 = eluf(fmaf(xv, wa.y, ba.y));
    float h2 = eluf(fmaf(xv, wa.z, ba.z));
    float h3 = eluf(fmaf(xv, wa.w, ba.w));
    float h4 = eluf(fmaf(xv, wb.x, bb.x));
    float h5 = eluf(fmaf(xv, wb.y, bb.y));
    float h6 = eluf(fmaf(xv, wb.z, bb.z));
    float h7 = eluf(fmaf(xv, wb.w, bb.w));
    uint4 pk;
    pk.x = f2bf(h0) | (f2bf(h1)<<16);
    pk.y = f2bf(h2) | (f2bf(h3)<<16);
    pk.z = f2bf(h4) | (f2bf(h5)<<16);
    pk.w = f2bf(h6) | (f2bf(h7)<<16);
    Apack[slot] = pk;
  }
}

// ---------------- prep: repack w2/wg (f32) -> bf16 B-fragment layout ----------------
__global__ __launch_bounds__(256) void k_prep(const float* __restrict__ w2,
                                              const float* __restrict__ wgm,
                                              uint4* __restrict__ Wpk){
  __shared__ float ssrc[2][128][32];
  const int tid = threadIdx.x;
  const int f = blockIdx.x, c = blockIdx.y;
  #pragma unroll
  for (int it = 0; it < 32; ++it){
    int idx = tid + it*256;
    int arr = idx >> 12;
    int rem = idx & 4095;
    int k = rem >> 5, dd = rem & 31;
    const float* src = arr ? wgm : w2;
    ssrc[arr][k][dd] = src[(f*HH + k)*DM + c*32 + dd];
  }
  __syncthreads();
  #pragma unroll
  for (int p = 0; p < 4; ++p){
    int oc = tid + p*256;
    int nt = oc>>9, ks = (oc>>6)&7, l = oc&63;
    int k0 = ks*16 + (l>>5)*8, dd = l&31;
    float v[8];
    #pragma unroll
    for (int j=0;j<8;++j) v[j] = ssrc[nt][k0+j][dd];
    uint4 pk;
    pk.x = f2bf(v[0]) | (f2bf(v[1])<<16);
    pk.y = f2bf(v[2]) | (f2bf(v[3])<<16);
    pk.z = f2bf(v[4]) | (f2bf(v[5])<<16);
    pk.w = f2bf(v[6]) | (f2bf(v[7])<<16);
    Wpk[(f*8 + c)*1024 + oc] = pk;
  }
}

// ---------------- pass1: GRN + LN + store shat(fp16) + pooled sums ----------------
// Barrier-free chunk loop: B-frags loaded global->reg (Wpk is frag-ordered),
// raw s staged fp16 in LDS (overlays Apack), LN applied at dump with mu/rs from LDS.
__global__ __launch_bounds__(256) void k_pass1(const float* __restrict__ x,  const float* __restrict__ w1,
    const float* __restrict__ b1, const float* __restrict__ b2, const float* __restrict__ bg,
    const float* __restrict__ wsk, const float* __restrict__ bsk,
    const float* __restrict__ lng, const float* __restrict__ lnb,
    const uint4* __restrict__ Wpk,
    float* __restrict__ pooled, uint4* __restrict__ stk4){
  __shared__ uint4 smem[4096];          // 64 KB: Apack (first 2048), then fp16 stage [128 t][256 d]
  __shared__ float muL[128], rsL[128];
  __shared__ float poolbuf[256];
  const int tid = threadIdx.x, lane = tid&63, wid = tid>>6;
  const int col = lane&31, q = lane>>5;
  const int f = blockIdx.y;
  const int tok0 = blockIdx.x*128;
  const int b = tok0 >> 9;
  poolbuf[tid] = 0.f;
  build_A<4>(smem, x, w1, b1, f, tok0, tid);
  __syncthreads();
  bf16x8 afr[8];
  #pragma unroll
  for (int ks=0; ks<8; ++ks) afr[ks] = __builtin_bit_cast(bf16x8, smem[(wid*8+ks)*64 + lane]);
  float xl = x[(tok0 + wid*32 + col)*NF + f];
  float xr[16];
  #pragma unroll
  for (int r=0;r<16;++r) xr[r] = qsel(xl, (r&3)+8*(r>>2), lane);
  __syncthreads();   // all Apack reads done; stage writes may begin
  __fp16* stage = (__fp16*)smem;   // [128 t][256 d]
  float sum[16], ssq[16];
  #pragma unroll
  for (int r=0;r<16;++r){ sum[r]=0.f; ssq[r]=0.f; }
  for (int c=0; c<8; ++c){
    const uint4* wb = Wpk + (f*8 + c)*1024;
    bf16x8 bf0[8], bf1[8];
    #pragma unroll
    for (int ks=0;ks<8;++ks) bf0[ks] = __builtin_bit_cast(bf16x8, wb[ks*64 + lane]);
    #pragma unroll
    for (int ks=0;ks<8;++ks) bf1[ks] = __builtin_bit_cast(bf16x8, wb[512 + ks*64 + lane]);
    f32x16 acc0 = {0.f}, acc1 = {0.f};
    #pragma unroll
    for (int ks=0;ks<8;++ks){
      acc0 = __builtin_amdgcn_mfma_f32_32x32x16_bf16(afr[ks], bf0[ks], acc0, 0,0,0);
      acc1 = __builtin_amdgcn_mfma_f32_32x32x16_bf16(afr[ks], bf1[ks], acc1, 0,0,0);
    }
    const int d = c*32 + col;
    const float b2v = b2[f*DM+d], bgv = bg[f*DM+d];
    const float wsv = wsk[f*DM+d], bsv = bsk[f*DM+d];
    #pragma unroll
    for (int i=0;i<8;++i){
      const int r0 = 2*i, r1 = 2*i+1;
      const int m0 = (r0&3) + 8*(i>>1) + 4*q;
      const int t0 = wid*32 + m0;
      float sv0 = fmaf(xr[r0], wsv, bsv) + sigm(acc1[r0]+bgv)*(acc0[r0]+b2v);
      float sv1 = fmaf(xr[r1], wsv, bsv) + sigm(acc1[r1]+bgv)*(acc0[r1]+b2v);
      sum[r0] += sv0; ssq[r0] = fmaf(sv0, sv0, ssq[r0]);
      sum[r1] += sv1; ssq[r1] = fmaf(sv1, sv1, ssq[r1]);
      stage[ t0   *256 + d] = (__fp16)sv0;
      stage[(t0+1)*256 + d] = (__fp16)sv1;
    }
  }
  // LN stats: butterfly over 32 cols within each q-half
  #pragma unroll
  for (int r=0;r<16;++r){
    float s1 = sum[r], s2 = ssq[r];
    s1 += __shfl_xor(s1,1);  s2 += __shfl_xor(s2,1);
    s1 += __shfl_xor(s1,2);  s2 += __shfl_xor(s2,2);
    s1 += __shfl_xor(s1,4);  s2 += __shfl_xor(s2,4);
    s1 += __shfl_xor(s1,8);  s2 += __shfl_xor(s2,8);
    s1 += __shfl_xor(s1,16); s2 += __shfl_xor(s2,16);
    float mu = s1 * (1.f/256.f);
    float var = fmaf(-mu, mu, s2*(1.f/256.f));
    sum[r] = mu;
    ssq[r] = rsqrtf(fmaxf(var, 0.f) + EPS);
  }
  if (col == 0){
    #pragma unroll
    for (int r=0;r<16;++r){
      int m = (r&3) + 8*(r>>2) + 4*q;
      muL[wid*32 + m] = sum[r];
      rsL[wid*32 + m] = ssq[r];
    }
  }
  __syncthreads();
  // dump: apply LN, write shat fp16 [f][t][d] coalesced, accumulate pooled
  const int oc = tid & 31;          // d-octet, constant per thread
  float4 ga = *(const float4*)(lng + f*DM + oc*8);
  float4 gb = *(const float4*)(lng + f*DM + oc*8 + 4);
  float4 ba = *(const float4*)(lnb + f*DM + oc*8);
  float4 bb = *(const float4*)(lnb + f*DM + oc*8 + 4);
  float gj[8] = {ga.x,ga.y,ga.z,ga.w,gb.x,gb.y,gb.z,gb.w};
  float bj[8] = {ba.x,ba.y,ba.z,ba.w,bb.x,bb.y,bb.z,bb.w};
  float ps[8];
  #pragma unroll
  for (int j=0;j<8;++j) ps[j]=0.f;
  #pragma unroll
  for (int p=0;p<16;++p){
    int slot = tid + p*256;          // [t(128)][oc(32)]
    int t = slot >> 5;
    uint4 v = smem[slot];
    f16x8 s8 = __builtin_bit_cast(f16x8, v);
    float mu = muL[t], rs = rsL[t];
    float nmr = -mu*rs;
    float sh[8];
    #pragma unroll
    for (int j=0;j<8;++j){
      sh[j] = fmaf(fmaf((float)s8[j], rs, nmr), gj[j], bj[j]);
      ps[j] += sh[j];
    }
    uint4 pk;
    pk.x = __builtin_bit_cast(unsigned, __builtin_amdgcn_cvt_pkrtz(sh[0], sh[1]));
    pk.y = __builtin_bit_cast(unsigned, __builtin_amdgcn_cvt_pkrtz(sh[2], sh[3]));
    pk.z = __builtin_bit_cast(unsigned, __builtin_amdgcn_cvt_pkrtz(sh[4], sh[5]));
    pk.w = __builtin_bit_cast(unsigned, __builtin_amdgcn_cvt_pkrtz(sh[6], sh[7]));
    stk4[(size_t)f*262144 + (size_t)(tok0 + t)*32 + oc] = pk;
  }
  #pragma unroll
  for (int j=0;j<8;++j) atomicAdd(&poolbuf[oc*8 + j], ps[j]);
  __syncthreads();
  atomicAdd(&pooled[b*8192 + f*DM + tid], poolbuf[tid]);
}

// ---------------- pass2a: flat_pooled @ W1 / @ Ws (split-K partials) ----------------
__global__ __launch_bounds__(256) void k_pass2a(const float* __restrict__ pooled,
    const float* __restrict__ W1, const float* __restrict__ Wsm,
    float* __restrict__ hw_pre, float* __restrict__ sk_pre){
  __shared__ float fl[512];
  const int tid = threadIdx.x;
  const int b = blockIdx.x;
  const int k0 = blockIdx.y * 512;
  fl[tid]       = pooled[b*8192 + k0 + tid]       * (1.f/512.f);
  fl[tid+256]   = pooled[b*8192 + k0 + tid + 256] * (1.f/512.f);
  __syncthreads();
  float acc = 0.f;
  const float* wcol = W1 + (size_t)k0*DM + tid;
  #pragma unroll 4
  for (int i=0;i<512;++i) acc = fmaf(fl[i], wcol[(size_t)i*DM], acc);
  atomicAdd(&hw_pre[b*DM + tid], acc);
  const int colj = tid & 31, sub = tid >> 5;
  float acc2 = 0.f;
  const float* wscol = Wsm + (size_t)(k0 + sub*64)*NF + colj;
  const float* fls = fl + sub*64;
  #pragma unroll 4
  for (int i=0;i<64;++i) acc2 = fmaf(fls[i], wscol[(size_t)i*NF], acc2);
  atomicAdd(&sk_pre[b*NF + colj], acc2);
}

// ---------------- pass2b: weight GRN + LN + softmax -> weights ----------------
__global__ __launch_bounds__(64) void k_pass2b(const float* __restrict__ hw_pre, const float* __restrict__ sk_pre,
    const float* __restrict__ B1, const float* __restrict__ W2, const float* __restrict__ B2,
    const float* __restrict__ Wg, const float* __restrict__ Bg, const float* __restrict__ Bs,
    const float* __restrict__ LNg, const float* __restrict__ LNb,
    float* __restrict__ out, float* __restrict__ wsel){
  __shared__ float hw[256];
  const int tid = threadIdx.x, b = blockIdx.x;
  for (int i=tid;i<256;i+=64) hw[i] = eluf(hw_pre[b*DM+i] + B1[i]);
  __syncthreads();
  if (tid < 32){
    const int j = tid;
    float ap = B2[j], ag = Bg[j];
    #pragma unroll 4
    for (int i=0;i<256;++i){ float h = hw[i]; ap = fmaf(h, W2[i*NF+j], ap); ag = fmaf(h, Wg[i*NF+j], ag); }
    float gw = sigm(ag);
    float v = sk_pre[b*NF+j] + Bs[j] + gw*ap;
    float s1 = v;
    s1 += __shfl_xor(s1,1); s1 += __shfl_xor(s1,2); s1 += __shfl_xor(s1,4); s1 += __shfl_xor(s1,8); s1 += __shfl_xor(s1,16);
    float mean = s1*(1.f/32.f);
    float dv = v - mean;
    float s2 = dv*dv;
    s2 += __shfl_xor(s2,1); s2 += __shfl_xor(s2,2); s2 += __shfl_xor(s2,4); s2 += __shfl_xor(s2,8); s2 += __shfl_xor(s2,16);
    float wn = fmaf(dv * rsqrtf(s2*(1.f/32.f) + EPS), LNg[j], LNb[j]);
    float mx = wn;
    mx = fmaxf(mx, __shfl_xor(mx,1)); mx = fmaxf(mx, __shfl_xor(mx,2)); mx = fmaxf(mx, __shfl_xor(mx,4));
    mx = fmaxf(mx, __shfl_xor(mx,8)); mx = fmaxf(mx, __shfl_xor(mx,16));
    float e = __expf(wn - mx);
    float se = e;
    se += __shfl_xor(se,1); se += __shfl_xor(se,2); se += __shfl_xor(se,4); se += __shfl_xor(se,8); se += __shfl_xor(se,16);
    float wgt = e / se;
    out[OUT_W_OFF + b*NF + j] = wgt;
    wsel[b*NF + j] = wgt;
  }
}

// ---------------- combine: out[t,d] = sum_f w[b,f] * shat[f,t,d] ----------------
// One token per wave; 16 independent uint4 loads per lane (f-half per 32-lane group).
__global__ __launch_bounds__(256) void k_comb(const uint4* __restrict__ stk4,
    const float* __restrict__ wsel, float* __restrict__ out){
  __shared__ float wloc[NF];
  const int tid = threadIdx.x, lane = tid&63;
  const int t = blockIdx.x*4 + (tid>>6);
  const int b = t >> 9;
  if (tid < NF) wloc[tid] = wsel[b*NF + tid];
  __syncthreads();
  const int oc = lane&31, fh = lane>>5;
  float acc[8];
  #pragma unroll
  for (int j=0;j<8;++j) acc[j]=0.f;
  #pragma unroll
  for (int j=0;j<16;++j){
    int f = fh*16 + j;
    uint4 v = stk4[(size_t)f*262144 + (size_t)t*32 + oc];
    f16x8 hv = __builtin_bit_cast(f16x8, v);
    float wf = wloc[f];
    #pragma unroll
    for (int jj=0;jj<8;++jj) acc[jj] = fmaf(wf, (float)hv[jj], acc[jj]);
  }
  #pragma unroll
  for (int jj=0;jj<8;++jj) acc[jj] += __shfl_xor(acc[jj], 32);
  if (fh == 0){
    float4* o = (float4*)(out + (size_t)t*DM + oc*8);
    o[0] = make_float4(acc[0],acc[1],acc[2],acc[3]);
    o[1] = make_float4(acc[4],acc[5],acc[6],acc[7]);
  }
}

extern "C" void kernel_launch(void* const* d_in, const int* in_sizes, int n_in,
                              void* d_out, int out_size, void* d_ws, size_t ws_size,
                              hipStream_t stream) {
  const float* x   = (const float*)d_in[0];
  const float* w1  = (const float*)d_in[1];
  const float* b1  = (const float*)d_in[2];
  const float* w2  = (const float*)d_in[3];
  const float* b2  = (const float*)d_in[4];
  const float* wgm = (const float*)d_in[5];
  const float* bg  = (const float*)d_in[6];
  const float* wsk = (const float*)d_in[7];
  const float* bsk = (const float*)d_in[8];
  const float* lng = (const float*)d_in[9];
  const float* lnb = (const float*)d_in[10];
  const float* W1  = (const float*)d_in[11];
  const float* B1  = (const float*)d_in[12];
  const float* W2  = (const float*)d_in[13];
  const float* B2  = (const float*)d_in[14];
  const float* Wg  = (const float*)d_in[15];
  const float* Bg  = (const float*)d_in[16];
  const float* Wsm = (const float*)d_in[17];
  const float* Bs  = (const float*)d_in[18];
  const float* LNg = (const float*)d_in[19];
  const float* LNb = (const float*)d_in[20];
  float* out = (float*)d_out;

  char* ws = (char*)d_ws;
  uint4* Wpk    = (uint4*)ws;                     // 4 MB bf16-packed weights
  uint4* stk4   = (uint4*)(ws + 4194304);         // 128 MiB fp16 shat [f][t][d]
  float* pooled = (float*)(ws + 138412032);       // 512 KB
  float* hw_pre = (float*)(ws + 138936320);       // 16 KB
  float* sk_pre = (float*)(ws + 138952704);       // 2 KB
  float* wsel   = (float*)(ws + 138954752);       // 2 KB

  (void)hipMemsetAsync(pooled, 0, 524288, stream);
  (void)hipMemsetAsync(hw_pre, 0, 16384 + 2048, stream);

  k_prep<<<dim3(32,8), 256, 0, stream>>>(w2, wgm, Wpk);
  k_pass1<<<dim3(64,32), 256, 0, stream>>>(x, w1, b1, b2, bg, wsk, bsk, lng, lnb,
                                           Wpk, pooled, stk4);
  k_pass2a<<<dim3(16,16), 256, 0, stream>>>(pooled, W1, Wsm, hw_pre, sk_pre);
  k_pass2b<<<16, 64, 0, stream>>>(hw_pre, sk_pre, B1, W2, B2, Wg, Bg, Bs, LNg, LNb, out, wsel);
  k_comb<<<2048, 256, 0, stream>>>(stk4, wsel, out);
}